// Round 4
// baseline (125.466 us; speedup 1.0000x reference)
//
#include <hip/hip_runtime.h>
#include <math.h>

#define NB 8
#define NC 3
#define HH 144
#define WW 144
#define NPAT 2304            // 48*48 patches per 144x144 image
#define NPTOT (NB * NPAT)    // 18432
#define MCAT 3024            // real candidates: 2304 + 576 + 144
#define MCATP 3072           // padded (48 guard cols, y2 = 1e30)
#define CHALF 1536           // candidates per block (half split)
#define CHUNK 384            // candidates staged per LDS round
#define ROUNDS 4             // CHALF / CHUNK
#define STEPS 3              // CHUNK / (32 lanes * 4 cand)
#define PPT 3                // patches per 32-lane group
#define GROUPS 8             // groups per 256-thread block
#define PPB (PPT * GROUPS)   // 24 patches per block
#define BLOCKS_PER_B (NPAT / PPB)            // 96
#define NBLK_SCORE (NB * BLOCKS_PER_B * 2)   // 1536 (x2: candidate halves)

typedef float f2 __attribute__((ext_vector_type(2)));

__device__ __forceinline__ int iclamp(int v, int lo, int hi) {
    return v < lo ? lo : (v > hi ? hi : v);
}

// gram of a 3x27 patch block -> 9 values, /27 (same op order as reference)
__device__ __forceinline__ void gram9(const float p[3][9], float g[9]) {
#pragma unroll
    for (int c = 0; c < 3; c++)
#pragma unroll
        for (int e = 0; e < 3; e++) {
            float s = 0.0f;
#pragma unroll
            for (int q = 0; q < 9; q++) s += p[c][q] * p[e][q];
            g[c * 3 + e] = s / 27.0f;
        }
}

// store candidate gram transposed [b][10][MCATP], row 9 = y2
__device__ __forceinline__ void store_cand(float* __restrict__ p2cT, int b, int m,
                                           const float g[9]) {
    float y2 = 0.0f;
#pragma unroll
    for (int j = 0; j < 9; j++) {
        p2cT[((size_t)b * 10 + j) * MCATP + m] = g[j];
        y2 += g[j] * g[j];
    }
    p2cT[((size_t)b * 10 + 9) * MCATP + m] = y2;
}

// ---- one kernel: direct patches (x, gt) + fused-resize patches (gt/2, gt/4) + guards
__global__ void patch_all(const float* __restrict__ x, const float* __restrict__ gt,
                          float* __restrict__ p1, float* __restrict__ p2cT) {
    const int R0 = NPTOT;        // x  -> p1
    const int R1 = NPTOT;        // gt -> cand m = n
    const int R2 = NB * 576;     // gt_2 fused -> m = 2304 + n
    const int R3 = NB * 144;     // gt_4 fused -> m = 2880 + n
    const int R4 = NB * 48;      // guard cols
    int idx = blockIdx.x * blockDim.x + threadIdx.x;
    if (idx >= R0 + R1 + R2 + R3 + R4) return;

    float p[3][9], g[9];

    if (idx < R0 + R1) {                       // direct 3x3 patches of x or gt
        const float* src = (idx < R0) ? x : gt;
        int li = (idx < R0) ? idx : idx - R0;
        int b = li / NPAT, n = li % NPAT;
        int ph = n / 48, pw = n % 48;
#pragma unroll
        for (int c = 0; c < 3; c++) {
            const float* s = src + ((size_t)b * NC + c) * HH * WW + (size_t)(ph * 3) * WW + pw * 3;
#pragma unroll
            for (int i = 0; i < 3; i++)
#pragma unroll
                for (int j = 0; j < 3; j++)
                    p[c][i * 3 + j] = s[i * WW + j];
        }
        gram9(p, g);
        if (idx < R0) {
            float* d = p1 + (size_t)li * 9;
#pragma unroll
            for (int j = 0; j < 9; j++) d[j] = g[j];
        } else {
            store_cand(p2cT, b, n, g);
        }
        return;
    }
    if (idx < R0 + R1 + R2) {                  // gt_2 (72x72) patches, resize fused
        int li = idx - R0 - R1;
        int b = li / 576, n = li % 576;
        int ph = n / 24, pw = n % 24;
#pragma unroll
        for (int c = 0; c < 3; c++) {
            const float* G = gt + ((size_t)b * NC + c) * HH * WW;
            float tmp[3][8];
#pragma unroll
            for (int i = 0; i < 3; i++) {
                int rb = 6 * ph - 1 + 2 * i;   // H-pass taps rb..rb+3 (clamped)
                int r0 = iclamp(rb + 0, 0, HH - 1) * WW;
                int r1 = iclamp(rb + 1, 0, HH - 1) * WW;
                int r2 = iclamp(rb + 2, 0, HH - 1) * WW;
                int r3 = iclamp(rb + 3, 0, HH - 1) * WW;
#pragma unroll
                for (int cc = 0; cc < 8; cc++) {
                    int col = iclamp(6 * pw - 1 + cc, 0, WW - 1);
                    float a = 0.0f;
                    a += -0.09375f * G[r0 + col];
                    a +=  0.59375f * G[r1 + col];
                    a +=  0.59375f * G[r2 + col];
                    a += -0.09375f * G[r3 + col];
                    tmp[i][cc] = a;
                }
            }
#pragma unroll
            for (int i = 0; i < 3; i++)
#pragma unroll
                for (int j = 0; j < 3; j++) {
                    float a = 0.0f;
                    a += -0.09375f * tmp[i][2 * j + 0];
                    a +=  0.59375f * tmp[i][2 * j + 1];
                    a +=  0.59375f * tmp[i][2 * j + 2];
                    a += -0.09375f * tmp[i][2 * j + 3];
                    p[c][i * 3 + j] = a;
                }
        }
        gram9(p, g);
        store_cand(p2cT, b, NPAT + n, g);
        return;
    }
    if (idx < R0 + R1 + R2 + R3) {             // gt_4 (36x36) patches, resize fused
        int li = idx - R0 - R1 - R2;
        int b = li / 144, n = li % 144;
        int ph = n / 12, pw = n % 12;
#pragma unroll
        for (int c = 0; c < 3; c++) {
            const float* G = gt + ((size_t)b * NC + c) * HH * WW;
            float tmp[3][12];
#pragma unroll
            for (int i = 0; i < 3; i++) {
                int rb = 12 * ph + 4 * i;      // taps rb..rb+3, always in range
#pragma unroll
                for (int cc = 0; cc < 12; cc++) {
                    int col = 12 * pw + cc;
                    float a = 0.0f;
                    a += -0.09375f * G[(rb + 0) * WW + col];
                    a +=  0.59375f * G[(rb + 1) * WW + col];
                    a +=  0.59375f * G[(rb + 2) * WW + col];
                    a += -0.09375f * G[(rb + 3) * WW + col];
                    tmp[i][cc] = a;
                }
            }
#pragma unroll
            for (int i = 0; i < 3; i++)
#pragma unroll
                for (int j = 0; j < 3; j++) {
                    float a = 0.0f;
                    a += -0.09375f * tmp[i][4 * j + 0];
                    a +=  0.59375f * tmp[i][4 * j + 1];
                    a +=  0.59375f * tmp[i][4 * j + 2];
                    a += -0.09375f * tmp[i][4 * j + 3];
                    p[c][i * 3 + j] = a;
                }
        }
        gram9(p, g);
        store_cand(p2cT, b, NPAT + 576 + n, g);
        return;
    }
    // guard columns: cand = 0, y2 = 1e30 (never wins, keeps staging branch-free)
    {
        int li = idx - R0 - R1 - R2 - R3;
        int b = li / 48, m = MCAT + li % 48;
#pragma unroll
        for (int j = 0; j < 9; j++) p2cT[((size_t)b * 10 + j) * MCATP + m] = 0.0f;
        p2cT[((size_t)b * 10 + 9) * MCATP + m] = 1e30f;
    }
}

// ---- score + argmin over one candidate half; writes per-patch (best, idx)
__global__ __launch_bounds__(256) void score_kernel(const float* __restrict__ p1,
                                                    const float* __restrict__ p2cT,
                                                    float* __restrict__ best_s,
                                                    int* __restrict__ best_i) {
    __shared__ float candT[10][CHUNK];   // rows 0..8 = gram planes, row 9 = y2

    int t     = threadIdx.x;
    int slice = t & 31;
    int grp   = t >> 5;
    int blk   = blockIdx.x;
    int b     = blk / (2 * BLOCKS_PER_B);
    int r     = blk % (2 * BLOCKS_PER_B);
    int half  = r / BLOCKS_PER_B;
    int bb    = r % BLOCKS_PER_B;
    int nbase = bb * PPB + grp * PPT;

    const float* PB = p2cT + (size_t)b * 10 * MCATP;

    float a1[PPT][9], a2[PPT][9], x21[PPT], x22[PPT];
#pragma unroll
    for (int p = 0; p < PPT; p++) {
        int n = nbase + p;
        const float* P1 = p1 + ((size_t)b * NPAT + n) * 9;
        float s1 = 0.0f;
#pragma unroll
        for (int j = 0; j < 9; j++) {
            a1[p][j] = P1[j];
            a2[p][j] = PB[(size_t)j * MCATP + n];   // cand rows [0,2304) == p2
        }
#pragma unroll
        for (int j = 0; j < 9; j++) s1 += a1[p][j] * a1[p][j];
        x21[p] = s1;
        x22[p] = PB[(size_t)9 * MCATP + n];
    }

    float best[PPT];
    int   besti[PPT];
#pragma unroll
    for (int p = 0; p < PPT; p++) { best[p] = INFINITY; besti[p] = 0x7fffffff; }

    for (int rd = 0; rd < ROUNDS; rd++) {
        int cb = half * CHALF + rd * CHUNK;
        // stage 10 planes x CHUNK, pure float4, branch-free (guards valid)
        for (int i = t; i < 10 * (CHUNK / 4); i += 256) {
            int plane = i / (CHUNK / 4), c4 = i - plane * (CHUNK / 4);
            float4 v = *(const float4*)&PB[(size_t)plane * MCATP + cb + c4 * 4];
            *(float4*)&candT[plane][c4 * 4] = v;
        }
        __syncthreads();

#pragma unroll
        for (int s = 0; s < STEPS; s++) {
            int cl = s * 128 + slice * 4;
            float4 y4 = *(const float4*)&candT[9][cl];
            f2 y2a = {y4.x, y4.y};
            f2 y2b = {y4.z, y4.w};
            f2 d1a[PPT], d1b[PPT], d2a[PPT], d2b[PPT];
#pragma unroll
            for (int p = 0; p < PPT; p++) {
                d1a[p] = (f2){0.0f, 0.0f}; d1b[p] = (f2){0.0f, 0.0f};
                d2a[p] = (f2){0.0f, 0.0f}; d2b[p] = (f2){0.0f, 0.0f};
            }
#pragma unroll
            for (int j = 0; j < 9; j++) {
                float4 v4 = *(const float4*)&candT[j][cl];
                f2 va = {v4.x, v4.y};
                f2 vb = {v4.z, v4.w};
#pragma unroll
                for (int p = 0; p < PPT; p++) {
                    d1a[p] += a1[p][j] * va;
                    d1b[p] += a1[p][j] * vb;
                    d2a[p] += a2[p][j] * va;
                    d2b[p] += a2[p][j] * vb;
                }
            }
            int cg = cb + cl;
#pragma unroll
            for (int p = 0; p < PPT; p++) {
                f2 xs1 = {x21[p], x21[p]};
                f2 xs2 = {x22[p], x22[p]};
                f2 s1a = (xs1 + y2a) - 2.0f * d1a[p];
                f2 s1b = (xs1 + y2b) - 2.0f * d1b[p];
                f2 s2a = (xs2 + y2a) - 2.0f * d2a[p];
                f2 s2b = (xs2 + y2b) - 2.0f * d2b[p];
                f2 sca = s1a + s2a;
                f2 scb = s1b + s2b;
                // ascending cg within lane: strict < keeps first min (tie-break free)
                if (sca.x < best[p]) { best[p] = sca.x; besti[p] = cg + 0; }
                if (sca.y < best[p]) { best[p] = sca.y; besti[p] = cg + 1; }
                if (scb.x < best[p]) { best[p] = scb.x; besti[p] = cg + 2; }
                if (scb.y < best[p]) { best[p] = scb.y; besti[p] = cg + 3; }
            }
        }
        __syncthreads();
    }

    // lexicographic (score, idx) min across the 32 lanes of the group
#pragma unroll
    for (int p = 0; p < PPT; p++) {
#pragma unroll
        for (int m = 1; m < 32; m <<= 1) {
            float ob = __shfl_xor(best[p], m);
            int   oi = __shfl_xor(besti[p], m);
            if (ob < best[p] || (ob == best[p] && oi < besti[p])) { best[p] = ob; besti[p] = oi; }
        }
        if (slice == 0) {
            size_t idx = (size_t)half * NPTOT + (size_t)b * NPAT + nbase + p;
            best_s[idx] = best[p];
            best_i[idx] = besti[p];
        }
    }
}

// ---- merge the two candidate-half results, compute per-patch L1
__global__ void merge_kernel(const float* __restrict__ p1, const float* __restrict__ p2cT,
                             const float* __restrict__ best_s, const int* __restrict__ best_i,
                             float* __restrict__ l1) {
    int gp = blockIdx.x * blockDim.x + threadIdx.x;
    if (gp >= NPTOT) return;
    int b = gp / NPAT;
    float s0 = best_s[gp];
    float s1 = best_s[NPTOT + gp];
    int   i0 = best_i[gp];
    int   i1 = best_i[NPTOT + gp];
    int bi = (s1 < s0 || (s1 == s0 && i1 < i0)) ? i1 : i0;   // half0 wins ties (lower idx)
    const float* P1 = p1 + (size_t)gp * 9;
    const float* PB = p2cT + (size_t)b * 10 * MCATP;
    float l = 0.0f;
#pragma unroll
    for (int j = 0; j < 9; j++) l += fabsf(P1[j] - PB[(size_t)j * MCATP + bi]);
    l1[gp] = l;
}

__global__ void final_kernel(const float* __restrict__ l1, float* __restrict__ out) {
    __shared__ float wsum[4];
    int t = threadIdx.x;
    float s = 0.0f;
    for (int i = t; i < NPTOT; i += 256) s += l1[i];
#pragma unroll
    for (int m = 1; m < 64; m <<= 1) s += __shfl_xor(s, m);
    if ((t & 63) == 0) wsum[t >> 6] = s;
    __syncthreads();
    if (t == 0) out[0] = ((wsum[0] + wsum[1]) + (wsum[2] + wsum[3])) / 165888.0f;
}

extern "C" void kernel_launch(void* const* d_in, const int* in_sizes, int n_in,
                              void* d_out, int out_size, void* d_ws, size_t ws_size,
                              hipStream_t stream) {
    const float* x  = (const float*)d_in[0];
    const float* gt = (const float*)d_in[1];
    float* out = (float*)d_out;

    float* ws     = (float*)d_ws;
    float* p1     = ws;                               // [18432,9]     = 165888
    float* p2cT   = p1 + (size_t)NPTOT * 9;           // [8,10,3072]   = 245760
    float* best_s = p2cT + (size_t)NB * 10 * MCATP;   // [2,18432]     =  36864
    int*   best_i = (int*)(best_s + 2 * NPTOT);       // [2,18432]     =  36864
    float* l1     = (float*)(best_i + 2 * NPTOT);     // [18432]

    {
        int tot = NPTOT + NPTOT + NB * 576 + NB * 144 + NB * 48;   // 43008
        patch_all<<<(tot + 255) / 256, 256, 0, stream>>>(x, gt, p1, p2cT);
    }
    score_kernel<<<NBLK_SCORE, 256, 0, stream>>>(p1, p2cT, best_s, best_i);
    merge_kernel<<<(NPTOT + 255) / 256, 256, 0, stream>>>(p1, p2cT, best_s, best_i, l1);
    final_kernel<<<1, 256, 0, stream>>>(l1, out);
}

// Round 5
// 79.979 us; speedup vs baseline: 1.5687x; 1.5687x over previous
//
#include <hip/hip_runtime.h>
#include <math.h>

#define NB 8
#define NC 3
#define HH 144
#define WW 144
#define NPAT 2304            // 48*48 patches per 144x144 image
#define NPTOT (NB * NPAT)    // 18432
#define MCAT 3024            // real candidates: 2304 + 576 + 144
#define MCATP 3072           // padded (48 guard cols, y2 = 1e30)
#define CHALF 1536           // candidates per block (half split)
#define CHUNK 384            // candidates staged per LDS round
#define ROUNDS 4             // CHALF / CHUNK
#define STEPS 3              // CHUNK / (32 lanes * 4 cand)
#define PPT 3                // patches per 32-lane group
#define GROUPS 8             // groups per 256-thread block
#define PPB (PPT * GROUPS)   // 24 patches per block
#define BLOCKS_PER_B (NPAT / PPB)            // 96
#define NBLK_SCORE (NB * BLOCKS_PER_B * 2)   // 1536 (x2: candidate halves)

typedef float f2 __attribute__((ext_vector_type(2)));

__device__ __forceinline__ int iclamp(int v, int lo, int hi) {
    return v < lo ? lo : (v > hi ? hi : v);
}

// ---- fused bicubic H-pass for both scales (frac always 0.5 -> constant taps)
// wide-parallel: one thread per output pixel (latency fully hidden by TLP)
__global__ void resize_h_all(const float* __restrict__ gt,
                             float* __restrict__ tmp2, float* __restrict__ tmp4) {
    const int T2 = NB * NC * 72 * WW;
    const int T4 = NB * NC * 36 * WW;
    int idx = blockIdx.x * blockDim.x + threadIdx.x;
    if (idx >= T2 + T4) return;
    int scale, H_out;
    float* dst;
    int li;
    if (idx < T2) { scale = 2; H_out = 72; dst = tmp2; li = idx; }
    else          { scale = 4; H_out = 36; dst = tmp4; li = idx - T2; }
    int w  = li % WW;
    int h  = (li / WW) % H_out;
    int bc = li / (WW * H_out);
    int t0 = scale * h + (scale >> 1) - 2;
    const float* s = gt + (size_t)bc * HH * WW + w;
    float acc = 0.0f;
    acc += -0.09375f * s[(size_t)iclamp(t0 + 0, 0, HH - 1) * WW];
    acc +=  0.59375f * s[(size_t)iclamp(t0 + 1, 0, HH - 1) * WW];
    acc +=  0.59375f * s[(size_t)iclamp(t0 + 2, 0, HH - 1) * WW];
    acc += -0.09375f * s[(size_t)iclamp(t0 + 3, 0, HH - 1) * WW];
    dst[li] = acc;
}

// ---- fused bicubic W-pass for both scales
__global__ void resize_w_all(const float* __restrict__ tmp2, const float* __restrict__ tmp4,
                             float* __restrict__ gt2, float* __restrict__ gt4) {
    const int T2 = NB * NC * 72 * 72;
    const int T4 = NB * NC * 36 * 36;
    int idx = blockIdx.x * blockDim.x + threadIdx.x;
    if (idx >= T2 + T4) return;
    int scale, H, W_out;
    const float* src;
    float* dst;
    int li;
    if (idx < T2) { scale = 2; H = 72; W_out = 72; src = tmp2; dst = gt2; li = idx; }
    else          { scale = 4; H = 36; W_out = 36; src = tmp4; dst = gt4; li = idx - T2; }
    int w  = li % W_out;
    int h  = (li / W_out) % H;
    int bc = li / (W_out * H);
    int t0 = scale * w + (scale >> 1) - 2;
    const float* s = src + ((size_t)bc * H + h) * WW;
    float acc = 0.0f;
    acc += -0.09375f * s[iclamp(t0 + 0, 0, WW - 1)];
    acc +=  0.59375f * s[iclamp(t0 + 1, 0, WW - 1)];
    acc +=  0.59375f * s[iclamp(t0 + 2, 0, WW - 1)];
    acc += -0.09375f * s[iclamp(t0 + 3, 0, WW - 1)];
    dst[li] = acc;
}

// gram of one 3x3 patch -> 9 values, /27 (same op order as reference)
__device__ __forceinline__ void patch_gram(const float* __restrict__ src, int H, int W,
                                           int b, int n, float* __restrict__ g) {
    int PW = W / 3;
    int ph = n / PW, pw = n % PW;
    float p[3][9];
#pragma unroll
    for (int c = 0; c < 3; c++) {
        const float* s = src + ((size_t)b * NC + c) * H * W + (size_t)(ph * 3) * W + pw * 3;
#pragma unroll
        for (int i = 0; i < 3; i++)
#pragma unroll
            for (int j = 0; j < 3; j++)
                p[c][i * 3 + j] = s[i * W + j];
    }
#pragma unroll
    for (int c = 0; c < 3; c++)
#pragma unroll
        for (int e = 0; e < 3; e++) {
            float s = 0.0f;
#pragma unroll
            for (int q = 0; q < 9; q++) s += p[c][q] * p[e][q];
            g[c * 3 + e] = s / 27.0f;
        }
}

// store candidate gram transposed [b][10][MCATP], row 9 = y2
__device__ __forceinline__ void store_cand(float* __restrict__ p2cT, int b, int m,
                                           const float g[9]) {
    float y2 = 0.0f;
#pragma unroll
    for (int j = 0; j < 9; j++) {
        p2cT[((size_t)b * 10 + j) * MCATP + m] = g[j];
        y2 += g[j] * g[j];
    }
    p2cT[((size_t)b * 10 + 9) * MCATP + m] = y2;
}

// ---- all 4 patch extractions (reads precomputed gt2/gt4) + guard cols
__global__ void patch_all(const float* __restrict__ x, const float* __restrict__ gt,
                          const float* __restrict__ gt2, const float* __restrict__ gt4,
                          float* __restrict__ p1, float* __restrict__ p2cT) {
    const int R0 = NPTOT;        // x   -> p1
    const int R1 = NPTOT;        // gt  -> cand m = n
    const int R2 = NB * 576;     // gt2 -> m = 2304 + n
    const int R3 = NB * 144;     // gt4 -> m = 2880 + n
    int idx = blockIdx.x * blockDim.x + threadIdx.x;
    if (idx >= R0 + R1 + R2 + R3 + NB * 48) return;

    float g[9];
    if (idx < R0) {
        int b = idx / NPAT, n = idx % NPAT;
        patch_gram(x, 144, 144, b, n, g);
        float* d = p1 + (size_t)idx * 9;
#pragma unroll
        for (int j = 0; j < 9; j++) d[j] = g[j];
        return;
    }
    if (idx < R0 + R1) {
        int li = idx - R0;
        int b = li / NPAT, n = li % NPAT;
        patch_gram(gt, 144, 144, b, n, g);
        store_cand(p2cT, b, n, g);
        return;
    }
    if (idx < R0 + R1 + R2) {
        int li = idx - R0 - R1;
        int b = li / 576, n = li % 576;
        patch_gram(gt2, 72, 72, b, n, g);
        store_cand(p2cT, b, NPAT + n, g);
        return;
    }
    if (idx < R0 + R1 + R2 + R3) {
        int li = idx - R0 - R1 - R2;
        int b = li / 144, n = li % 144;
        patch_gram(gt4, 36, 36, b, n, g);
        store_cand(p2cT, b, NPAT + 576 + n, g);
        return;
    }
    // guard columns: cand = 0, y2 = 1e30 (never wins, keeps staging branch-free)
    {
        int li = idx - R0 - R1 - R2 - R3;
        int b = li / 48, m = MCAT + li % 48;
#pragma unroll
        for (int j = 0; j < 9; j++) p2cT[((size_t)b * 10 + j) * MCATP + m] = 0.0f;
        p2cT[((size_t)b * 10 + 9) * MCATP + m] = 1e30f;
    }
}

// ---- score + argmin over one candidate half; writes per-patch (best, idx)
__global__ __launch_bounds__(256) void score_kernel(const float* __restrict__ p1,
                                                    const float* __restrict__ p2cT,
                                                    float* __restrict__ best_s,
                                                    int* __restrict__ best_i) {
    __shared__ float candT[10][CHUNK];   // rows 0..8 = gram planes, row 9 = y2

    int t     = threadIdx.x;
    int slice = t & 31;
    int grp   = t >> 5;
    int blk   = blockIdx.x;
    int b     = blk / (2 * BLOCKS_PER_B);
    int r     = blk % (2 * BLOCKS_PER_B);
    int half  = r / BLOCKS_PER_B;
    int bb    = r % BLOCKS_PER_B;
    int nbase = bb * PPB + grp * PPT;

    const float* PB = p2cT + (size_t)b * 10 * MCATP;

    float a1[PPT][9], a2[PPT][9], x21[PPT], x22[PPT];
#pragma unroll
    for (int p = 0; p < PPT; p++) {
        int n = nbase + p;
        const float* P1 = p1 + ((size_t)b * NPAT + n) * 9;
        float s1 = 0.0f;
#pragma unroll
        for (int j = 0; j < 9; j++) {
            a1[p][j] = P1[j];
            a2[p][j] = PB[(size_t)j * MCATP + n];   // cand rows [0,2304) == p2
        }
#pragma unroll
        for (int j = 0; j < 9; j++) s1 += a1[p][j] * a1[p][j];
        x21[p] = s1;
        x22[p] = PB[(size_t)9 * MCATP + n];
    }

    float best[PPT];
    int   besti[PPT];
#pragma unroll
    for (int p = 0; p < PPT; p++) { best[p] = INFINITY; besti[p] = 0x7fffffff; }

    for (int rd = 0; rd < ROUNDS; rd++) {
        int cb = half * CHALF + rd * CHUNK;
        // stage 10 planes x CHUNK, pure float4, branch-free (guards valid)
        for (int i = t; i < 10 * (CHUNK / 4); i += 256) {
            int plane = i / (CHUNK / 4), c4 = i - plane * (CHUNK / 4);
            float4 v = *(const float4*)&PB[(size_t)plane * MCATP + cb + c4 * 4];
            *(float4*)&candT[plane][c4 * 4] = v;
        }
        __syncthreads();

#pragma unroll
        for (int s = 0; s < STEPS; s++) {
            int cl = s * 128 + slice * 4;
            float4 y4 = *(const float4*)&candT[9][cl];
            f2 y2a = {y4.x, y4.y};
            f2 y2b = {y4.z, y4.w};
            f2 d1a[PPT], d1b[PPT], d2a[PPT], d2b[PPT];
#pragma unroll
            for (int p = 0; p < PPT; p++) {
                d1a[p] = (f2){0.0f, 0.0f}; d1b[p] = (f2){0.0f, 0.0f};
                d2a[p] = (f2){0.0f, 0.0f}; d2b[p] = (f2){0.0f, 0.0f};
            }
#pragma unroll
            for (int j = 0; j < 9; j++) {
                float4 v4 = *(const float4*)&candT[j][cl];
                f2 va = {v4.x, v4.y};
                f2 vb = {v4.z, v4.w};
#pragma unroll
                for (int p = 0; p < PPT; p++) {
                    d1a[p] += a1[p][j] * va;
                    d1b[p] += a1[p][j] * vb;
                    d2a[p] += a2[p][j] * va;
                    d2b[p] += a2[p][j] * vb;
                }
            }
            int cg = cb + cl;
#pragma unroll
            for (int p = 0; p < PPT; p++) {
                f2 xs1 = {x21[p], x21[p]};
                f2 xs2 = {x22[p], x22[p]};
                f2 s1a = (xs1 + y2a) - 2.0f * d1a[p];
                f2 s1b = (xs1 + y2b) - 2.0f * d1b[p];
                f2 s2a = (xs2 + y2a) - 2.0f * d2a[p];
                f2 s2b = (xs2 + y2b) - 2.0f * d2b[p];
                f2 sca = s1a + s2a;
                f2 scb = s1b + s2b;
                // ascending cg within lane: strict < keeps first min (tie-break free)
                if (sca.x < best[p]) { best[p] = sca.x; besti[p] = cg + 0; }
                if (sca.y < best[p]) { best[p] = sca.y; besti[p] = cg + 1; }
                if (scb.x < best[p]) { best[p] = scb.x; besti[p] = cg + 2; }
                if (scb.y < best[p]) { best[p] = scb.y; besti[p] = cg + 3; }
            }
        }
        __syncthreads();
    }

    // lexicographic (score, idx) min across the 32 lanes of the group
#pragma unroll
    for (int p = 0; p < PPT; p++) {
#pragma unroll
        for (int m = 1; m < 32; m <<= 1) {
            float ob = __shfl_xor(best[p], m);
            int   oi = __shfl_xor(besti[p], m);
            if (ob < best[p] || (ob == best[p] && oi < besti[p])) { best[p] = ob; besti[p] = oi; }
        }
        if (slice == 0) {
            size_t idx = (size_t)half * NPTOT + (size_t)b * NPAT + nbase + p;
            best_s[idx] = best[p];
            best_i[idx] = besti[p];
        }
    }
}

// ---- merge the two candidate-half results, compute per-patch L1
__global__ void merge_kernel(const float* __restrict__ p1, const float* __restrict__ p2cT,
                             const float* __restrict__ best_s, const int* __restrict__ best_i,
                             float* __restrict__ l1) {
    int gp = blockIdx.x * blockDim.x + threadIdx.x;
    if (gp >= NPTOT) return;
    int b = gp / NPAT;
    float s0 = best_s[gp];
    float s1 = best_s[NPTOT + gp];
    int   i0 = best_i[gp];
    int   i1 = best_i[NPTOT + gp];
    int bi = (s1 < s0 || (s1 == s0 && i1 < i0)) ? i1 : i0;   // half0 wins ties (lower idx)
    const float* P1 = p1 + (size_t)gp * 9;
    const float* PB = p2cT + (size_t)b * 10 * MCATP;
    float l = 0.0f;
#pragma unroll
    for (int j = 0; j < 9; j++) l += fabsf(P1[j] - PB[(size_t)j * MCATP + bi]);
    l1[gp] = l;
}

__global__ void final_kernel(const float* __restrict__ l1, float* __restrict__ out) {
    __shared__ float wsum[4];
    int t = threadIdx.x;
    float s = 0.0f;
    for (int i = t; i < NPTOT; i += 256) s += l1[i];
#pragma unroll
    for (int m = 1; m < 64; m <<= 1) s += __shfl_xor(s, m);
    if ((t & 63) == 0) wsum[t >> 6] = s;
    __syncthreads();
    if (t == 0) out[0] = ((wsum[0] + wsum[1]) + (wsum[2] + wsum[3])) / 165888.0f;
}

extern "C" void kernel_launch(void* const* d_in, const int* in_sizes, int n_in,
                              void* d_out, int out_size, void* d_ws, size_t ws_size,
                              hipStream_t stream) {
    const float* x  = (const float*)d_in[0];
    const float* gt = (const float*)d_in[1];
    float* out = (float*)d_out;

    float* ws     = (float*)d_ws;
    float* tmp2   = ws;                               // [8,3,72,144]  = 248832
    float* tmp4   = tmp2 + NB * NC * 72 * 144;        // [8,3,36,144]  = 124416
    float* gt2    = tmp4 + NB * NC * 36 * 144;        // [8,3,72,72]   = 124416
    float* gt4    = gt2  + NB * NC * 72 * 72;         // [8,3,36,36]   =  31104
    float* p1     = gt4  + NB * NC * 36 * 36;         // [18432,9]     = 165888
    float* p2cT   = p1 + (size_t)NPTOT * 9;           // [8,10,3072]   = 245760
    float* best_s = p2cT + (size_t)NB * 10 * MCATP;   // [2,18432]     =  36864
    int*   best_i = (int*)(best_s + 2 * NPTOT);       // [2,18432]     =  36864
    float* l1     = (float*)(best_i + 2 * NPTOT);     // [18432]

    {
        int tot = NB * NC * 72 * WW + NB * NC * 36 * WW;
        resize_h_all<<<(tot + 255) / 256, 256, 0, stream>>>(gt, tmp2, tmp4);
    }
    {
        int tot = NB * NC * 72 * 72 + NB * NC * 36 * 36;
        resize_w_all<<<(tot + 255) / 256, 256, 0, stream>>>(tmp2, tmp4, gt2, gt4);
    }
    {
        int tot = NPTOT + NPTOT + NB * 576 + NB * 144 + NB * 48;   // 43008
        patch_all<<<(tot + 255) / 256, 256, 0, stream>>>(x, gt, gt2, gt4, p1, p2cT);
    }
    score_kernel<<<NBLK_SCORE, 256, 0, stream>>>(p1, p2cT, best_s, best_i);
    merge_kernel<<<(NPTOT + 255) / 256, 256, 0, stream>>>(p1, p2cT, best_s, best_i, l1);
    final_kernel<<<1, 256, 0, stream>>>(l1, out);
}

// Round 6
// 68.728 us; speedup vs baseline: 1.8256x; 1.1637x over previous
//
#include <hip/hip_runtime.h>
#include <math.h>

#define NB 8
#define NC 3
#define HH 144
#define WW 144
#define NPAT 2304            // 48*48 patches per 144x144 image
#define NPTOT (NB * NPAT)    // 18432
#define MCAT 3024            // real candidates: 2304 + 576 + 144
#define MCATP 3072           // padded (48 guard cols, T = 1e30)
#define CHALF 1536           // candidates per block (half split)
#define CHUNK 384            // candidates staged per LDS round
#define ROUNDS 4             // CHALF / CHUNK
#define STEPS 3              // CHUNK / (32 lanes * 4 cand)
#define PPT 6                // patches per 32-lane group
#define GROUPS 8             // groups per 256-thread block
#define PPB (PPT * GROUPS)   // 48 patches per block
#define BLOCKS_PER_B (NPAT / PPB)            // 48
#define NBLK_SCORE (NB * BLOCKS_PER_B * 2)   // 768 (x2: candidate halves)

typedef float f2 __attribute__((ext_vector_type(2)));

__device__ __forceinline__ int iclamp(int v, int lo, int hi) {
    return v < lo ? lo : (v > hi ? hi : v);
}

// ---- fused bicubic H-pass for both scales (frac always 0.5 -> constant taps)
// wide-parallel: one thread per output pixel (latency fully hidden by TLP)
__global__ void resize_h_all(const float* __restrict__ gt,
                             float* __restrict__ tmp2, float* __restrict__ tmp4) {
    const int T2 = NB * NC * 72 * WW;
    const int T4 = NB * NC * 36 * WW;
    int idx = blockIdx.x * blockDim.x + threadIdx.x;
    if (idx >= T2 + T4) return;
    int scale, H_out;
    float* dst;
    int li;
    if (idx < T2) { scale = 2; H_out = 72; dst = tmp2; li = idx; }
    else          { scale = 4; H_out = 36; dst = tmp4; li = idx - T2; }
    int w  = li % WW;
    int h  = (li / WW) % H_out;
    int bc = li / (WW * H_out);
    int t0 = scale * h + (scale >> 1) - 2;
    const float* s = gt + (size_t)bc * HH * WW + w;
    float acc = 0.0f;
    acc += -0.09375f * s[(size_t)iclamp(t0 + 0, 0, HH - 1) * WW];
    acc +=  0.59375f * s[(size_t)iclamp(t0 + 1, 0, HH - 1) * WW];
    acc +=  0.59375f * s[(size_t)iclamp(t0 + 2, 0, HH - 1) * WW];
    acc += -0.09375f * s[(size_t)iclamp(t0 + 3, 0, HH - 1) * WW];
    dst[li] = acc;
}

// ---- fused bicubic W-pass for both scales
__global__ void resize_w_all(const float* __restrict__ tmp2, const float* __restrict__ tmp4,
                             float* __restrict__ gt2, float* __restrict__ gt4) {
    const int T2 = NB * NC * 72 * 72;
    const int T4 = NB * NC * 36 * 36;
    int idx = blockIdx.x * blockDim.x + threadIdx.x;
    if (idx >= T2 + T4) return;
    int scale, H, W_out;
    const float* src;
    float* dst;
    int li;
    if (idx < T2) { scale = 2; H = 72; W_out = 72; src = tmp2; dst = gt2; li = idx; }
    else          { scale = 4; H = 36; W_out = 36; src = tmp4; dst = gt4; li = idx - T2; }
    int w  = li % W_out;
    int h  = (li / W_out) % H;
    int bc = li / (W_out * H);
    int t0 = scale * w + (scale >> 1) - 2;
    const float* s = src + ((size_t)bc * H + h) * WW;
    float acc = 0.0f;
    acc += -0.09375f * s[iclamp(t0 + 0, 0, WW - 1)];
    acc +=  0.59375f * s[iclamp(t0 + 1, 0, WW - 1)];
    acc +=  0.59375f * s[iclamp(t0 + 2, 0, WW - 1)];
    acc += -0.09375f * s[iclamp(t0 + 3, 0, WW - 1)];
    dst[li] = acc;
}

// gram of one 3x3 patch -> 9 values, /27 (same op order as reference)
__device__ __forceinline__ void patch_gram(const float* __restrict__ src, int H, int W,
                                           int b, int n, float* __restrict__ g) {
    int PW = W / 3;
    int ph = n / PW, pw = n % PW;
    float p[3][9];
#pragma unroll
    for (int c = 0; c < 3; c++) {
        const float* s = src + ((size_t)b * NC + c) * H * W + (size_t)(ph * 3) * W + pw * 3;
#pragma unroll
        for (int i = 0; i < 3; i++)
#pragma unroll
            for (int j = 0; j < 3; j++)
                p[c][i * 3 + j] = s[i * W + j];
    }
#pragma unroll
    for (int c = 0; c < 3; c++)
#pragma unroll
        for (int e = 0; e < 3; e++) {
            float s = 0.0f;
#pragma unroll
            for (int q = 0; q < 9; q++) s += p[c][q] * p[e][q];
            g[c * 3 + e] = s / 27.0f;
        }
}

// store candidate gram transposed [b][10][MCATP]; row 9 = T = 2*y2
__device__ __forceinline__ void store_cand(float* __restrict__ p2cT, int b, int m,
                                           const float g[9]) {
    float y2 = 0.0f;
#pragma unroll
    for (int j = 0; j < 9; j++) {
        p2cT[((size_t)b * 10 + j) * MCATP + m] = g[j];
        y2 += g[j] * g[j];
    }
    p2cT[((size_t)b * 10 + 9) * MCATP + m] = 2.0f * y2;
}

// ---- all 4 patch extractions (reads precomputed gt2/gt4) + guard cols
__global__ void patch_all(const float* __restrict__ x, const float* __restrict__ gt,
                          const float* __restrict__ gt2, const float* __restrict__ gt4,
                          float* __restrict__ p1, float* __restrict__ p2cT) {
    const int R0 = NPTOT;        // x   -> p1
    const int R1 = NPTOT;        // gt  -> cand m = n
    const int R2 = NB * 576;     // gt2 -> m = 2304 + n
    const int R3 = NB * 144;     // gt4 -> m = 2880 + n
    int idx = blockIdx.x * blockDim.x + threadIdx.x;
    if (idx >= R0 + R1 + R2 + R3 + NB * 48) return;

    float g[9];
    if (idx < R0) {
        int b = idx / NPAT, n = idx % NPAT;
        patch_gram(x, 144, 144, b, n, g);
        float* d = p1 + (size_t)idx * 9;
#pragma unroll
        for (int j = 0; j < 9; j++) d[j] = g[j];
        return;
    }
    if (idx < R0 + R1) {
        int li = idx - R0;
        int b = li / NPAT, n = li % NPAT;
        patch_gram(gt, 144, 144, b, n, g);
        store_cand(p2cT, b, n, g);
        return;
    }
    if (idx < R0 + R1 + R2) {
        int li = idx - R0 - R1;
        int b = li / 576, n = li % 576;
        patch_gram(gt2, 72, 72, b, n, g);
        store_cand(p2cT, b, NPAT + n, g);
        return;
    }
    if (idx < R0 + R1 + R2 + R3) {
        int li = idx - R0 - R1 - R2;
        int b = li / 144, n = li % 144;
        patch_gram(gt4, 36, 36, b, n, g);
        store_cand(p2cT, b, NPAT + 576 + n, g);
        return;
    }
    // guard columns: cand = 0, T = 1e30 (never wins, keeps staging branch-free)
    {
        int li = idx - R0 - R1 - R2 - R3;
        int b = li / 48, m = MCAT + li % 48;
#pragma unroll
        for (int j = 0; j < 9; j++) p2cT[((size_t)b * 10 + j) * MCATP + m] = 0.0f;
        p2cT[((size_t)b * 10 + 9) * MCATP + m] = 1e30f;
    }
}

// ---- score + argmin over one candidate half; writes per-patch (best, idx).
// sc = (Sp + T) + sum_j aa2[j]*v[j],  aa2 = -2*(a1+a2), Sp = |a1|^2+|a2|^2, T = 2*y2.
__global__ __launch_bounds__(256) void score_kernel(const float* __restrict__ p1,
                                                    const float* __restrict__ p2cT,
                                                    float* __restrict__ best_s,
                                                    int* __restrict__ best_i) {
    __shared__ float candT[10][CHUNK];   // rows 0..8 = gram planes, row 9 = T

    int t     = threadIdx.x;
    int slice = t & 31;
    int grp   = t >> 5;
    int blk   = blockIdx.x;
    int b     = blk / (2 * BLOCKS_PER_B);
    int r     = blk % (2 * BLOCKS_PER_B);
    int half  = r / BLOCKS_PER_B;
    int bb    = r % BLOCKS_PER_B;
    int nbase = bb * PPB + grp * PPT;

    const float* PB = p2cT + (size_t)b * 10 * MCATP;

    float aa2[PPT][9], Sp[PPT];
#pragma unroll
    for (int p = 0; p < PPT; p++) {
        int n = nbase + p;
        const float* P1 = p1 + ((size_t)b * NPAT + n) * 9;
        float x21 = 0.0f;
#pragma unroll
        for (int j = 0; j < 9; j++) {
            float a1 = P1[j];
            float a2 = PB[(size_t)j * MCATP + n];   // cand rows [0,2304) == p2
            aa2[p][j] = -2.0f * (a1 + a2);
            x21 += a1 * a1;
        }
        float x22 = 0.5f * PB[(size_t)9 * MCATP + n];   // T row = 2*y2 -> y2 exact
        Sp[p] = x21 + x22;
    }

    float best[PPT];
    int   besti[PPT];
#pragma unroll
    for (int p = 0; p < PPT; p++) { best[p] = INFINITY; besti[p] = 0x7fffffff; }

    for (int rd = 0; rd < ROUNDS; rd++) {
        int cb = half * CHALF + rd * CHUNK;
        // stage 10 planes x CHUNK, pure float4, branch-free (guards valid)
        for (int i = t; i < 10 * (CHUNK / 4); i += 256) {
            int plane = i / (CHUNK / 4), c4 = i - plane * (CHUNK / 4);
            float4 v = *(const float4*)&PB[(size_t)plane * MCATP + cb + c4 * 4];
            *(float4*)&candT[plane][c4 * 4] = v;
        }
        __syncthreads();

#pragma unroll
        for (int s = 0; s < STEPS; s++) {
            int cl = s * 128 + slice * 4;
            float4 t4 = *(const float4*)&candT[9][cl];
            f2 Ta = {t4.x, t4.y};
            f2 Tb = {t4.z, t4.w};
            f2 sa[PPT], sb[PPT];
#pragma unroll
            for (int p = 0; p < PPT; p++) { sa[p] = Sp[p] + Ta; sb[p] = Sp[p] + Tb; }
#pragma unroll
            for (int j = 0; j < 9; j++) {
                float4 v4 = *(const float4*)&candT[j][cl];
                f2 va = {v4.x, v4.y};
                f2 vb = {v4.z, v4.w};
#pragma unroll
                for (int p = 0; p < PPT; p++) {
                    sa[p] += aa2[p][j] * va;
                    sb[p] += aa2[p][j] * vb;
                }
            }
            int cg = cb + cl;
#pragma unroll
            for (int p = 0; p < PPT; p++) {
                // ascending cg within lane: strict < keeps first min
                if (sa[p].x < best[p]) { best[p] = sa[p].x; besti[p] = cg + 0; }
                if (sa[p].y < best[p]) { best[p] = sa[p].y; besti[p] = cg + 1; }
                if (sb[p].x < best[p]) { best[p] = sb[p].x; besti[p] = cg + 2; }
                if (sb[p].y < best[p]) { best[p] = sb[p].y; besti[p] = cg + 3; }
            }
        }
        __syncthreads();
    }

    // lexicographic (score, idx) min across the 32 lanes of the group
#pragma unroll
    for (int p = 0; p < PPT; p++) {
#pragma unroll
        for (int m = 1; m < 32; m <<= 1) {
            float ob = __shfl_xor(best[p], m);
            int   oi = __shfl_xor(besti[p], m);
            if (ob < best[p] || (ob == best[p] && oi < besti[p])) { best[p] = ob; besti[p] = oi; }
        }
        if (slice == 0) {
            size_t idx = (size_t)half * NPTOT + (size_t)b * NPAT + nbase + p;
            best_s[idx] = best[p];
            best_i[idx] = besti[p];
        }
    }
}

// ---- merge the two candidate-half results, compute per-patch L1
__global__ void merge_kernel(const float* __restrict__ p1, const float* __restrict__ p2cT,
                             const float* __restrict__ best_s, const int* __restrict__ best_i,
                             float* __restrict__ l1) {
    int gp = blockIdx.x * blockDim.x + threadIdx.x;
    if (gp >= NPTOT) return;
    int b = gp / NPAT;
    float s0 = best_s[gp];
    float s1 = best_s[NPTOT + gp];
    int   i0 = best_i[gp];
    int   i1 = best_i[NPTOT + gp];
    int bi = (s1 < s0 || (s1 == s0 && i1 < i0)) ? i1 : i0;   // half0 wins ties (lower idx)
    const float* P1 = p1 + (size_t)gp * 9;
    const float* PB = p2cT + (size_t)b * 10 * MCATP;
    float l = 0.0f;
#pragma unroll
    for (int j = 0; j < 9; j++) l += fabsf(P1[j] - PB[(size_t)j * MCATP + bi]);
    l1[gp] = l;
}

__global__ void final_kernel(const float* __restrict__ l1, float* __restrict__ out) {
    __shared__ float wsum[4];
    int t = threadIdx.x;
    float s = 0.0f;
    for (int i = t; i < NPTOT; i += 256) s += l1[i];
#pragma unroll
    for (int m = 1; m < 64; m <<= 1) s += __shfl_xor(s, m);
    if ((t & 63) == 0) wsum[t >> 6] = s;
    __syncthreads();
    if (t == 0) out[0] = ((wsum[0] + wsum[1]) + (wsum[2] + wsum[3])) / 165888.0f;
}

extern "C" void kernel_launch(void* const* d_in, const int* in_sizes, int n_in,
                              void* d_out, int out_size, void* d_ws, size_t ws_size,
                              hipStream_t stream) {
    const float* x  = (const float*)d_in[0];
    const float* gt = (const float*)d_in[1];
    float* out = (float*)d_out;

    float* ws     = (float*)d_ws;
    float* tmp2   = ws;                               // [8,3,72,144]  = 248832
    float* tmp4   = tmp2 + NB * NC * 72 * 144;        // [8,3,36,144]  = 124416
    float* gt2    = tmp4 + NB * NC * 36 * 144;        // [8,3,72,72]   = 124416
    float* gt4    = gt2  + NB * NC * 72 * 72;         // [8,3,36,36]   =  31104
    float* p1     = gt4  + NB * NC * 36 * 36;         // [18432,9]     = 165888
    float* p2cT   = p1 + (size_t)NPTOT * 9;           // [8,10,3072]   = 245760
    float* best_s = p2cT + (size_t)NB * 10 * MCATP;   // [2,18432]     =  36864
    int*   best_i = (int*)(best_s + 2 * NPTOT);       // [2,18432]     =  36864
    float* l1     = (float*)(best_i + 2 * NPTOT);     // [18432]

    {
        int tot = NB * NC * 72 * WW + NB * NC * 36 * WW;
        resize_h_all<<<(tot + 255) / 256, 256, 0, stream>>>(gt, tmp2, tmp4);
    }
    {
        int tot = NB * NC * 72 * 72 + NB * NC * 36 * 36;
        resize_w_all<<<(tot + 255) / 256, 256, 0, stream>>>(tmp2, tmp4, gt2, gt4);
    }
    {
        int tot = NPTOT + NPTOT + NB * 576 + NB * 144 + NB * 48;   // 43008
        patch_all<<<(tot + 255) / 256, 256, 0, stream>>>(x, gt, gt2, gt4, p1, p2cT);
    }
    score_kernel<<<NBLK_SCORE, 256, 0, stream>>>(p1, p2cT, best_s, best_i);
    merge_kernel<<<(NPTOT + 255) / 256, 256, 0, stream>>>(p1, p2cT, best_s, best_i, l1);
    final_kernel<<<1, 256, 0, stream>>>(l1, out);
}